// Round 1
// 653.624 us; speedup vs baseline: 1.0882x; 1.0882x over previous
//
#include <hip/hip_runtime.h>
#include <math.h>

#define SS 1024
#define DD 64
#define BH 64

typedef __attribute__((ext_vector_type(4))) float fx4;
typedef __attribute__((ext_vector_type(8))) short sx8;
typedef __attribute__((ext_vector_type(4))) short sx4;

__device__ __forceinline__ unsigned short f2bf(float x) {
  unsigned u = __builtin_bit_cast(unsigned, x);
  u += 0x7fffu + ((u >> 16) & 1u);
  return (unsigned short)(u >> 16);
}
__device__ __forceinline__ float bf2f(unsigned short h) {
  return __builtin_bit_cast(float, ((unsigned)h) << 16);
}

// ---------------------------------------------------------------------------
// Fully fused kernel. Per block: 64-row i-stripe, 4 waves.
//   pass 1: logits via MFMA (hi/lo bf16 split) -> rowSum += exp(logit)
//           (no max subtraction: logits <~45, exp fits fp32 comfortably)
//   pass 2: recompute logits, w = exp(x)*rowInv, write W, PV + skew-PV MFMA.
// Raw logits NEVER touch HBM (saves ~400 MB round-trip vs 2-kernel scheme).
// LDS (54528 B -> 3 blocks/CU):
//   region0 [0,36864):  {Khi,Klo,RK} (logits phase)  U  {vT,rvT,wA} (PV phase)
//   region1 [36864,54272): wSk (complement slots zeroed ONCE; constant posns)
//   rowInv[64] @54272.
// ---------------------------------------------------------------------------
__global__ __launch_bounds__(256, 3) void k_fused(
    const float* __restrict__ q, const float* __restrict__ k,
    const float* __restrict__ v, const float* __restrict__ RK,
    const float* __restrict__ RV, float* __restrict__ W, float* __restrict__ O) {
  // XCD-contiguous remap: XCD x -> bh in [8x, 8x+8)  (K/V working set ~4MB ~ L2)
  const int bid = (blockIdx.y << 4) | blockIdx.x;  // 1024 blocks, %8 == 0
  const int nb = ((bid & 7) << 7) | (bid >> 3);
  const int it = nb & 15, bh = nb >> 4;
  const int i0 = it << 6;

  __shared__ __align__(16) char smem[54272];
  __shared__ float rowInv[64];
  short* const sKh = (short*)smem;            // [64*72]
  short* const sKl = (short*)(smem + 9216);   // [64*72]
  short* const sRh = (short*)(smem + 18432);  // [128*72]
  short* const vT  = (short*)smem;            // [64*72]   (aliases sKh)
  short* const rvT = (short*)(smem + 9216);   // [64*136]  (aliases sKl/sRh)
  short* const wA  = (short*)(smem + 26624);  // [64*72]   (aliases sRh tail)
  short* const wSk = (short*)(smem + 36864);  // [64*136]  (exclusive)

  const int t = threadIdx.x;
  const int lane = t & 63, mt = t >> 6, quad = lane >> 4, lc = lane & 15;

  // phase 0: zero the fully-masked upper columns of W for our 64 rows
  {
    const int r = t >> 2, g = t & 3;
    float* Wrow = W + ((size_t)(bh * SS + i0 + r)) * SS;
    float4 z; z.x = z.y = z.z = z.w = 0.f;
    for (int j = (it + 1) * 64 + g * 4; j < SS; j += 16) *(float4*)(Wrow + j) = z;
  }

  // one-time: zero the never-valid wSk slots (positions constant across tiles).
  // Lane (quad,lc), row rr=quad*4+e owns u-slots {us0+16*kk}; valid kk in [A,A+3].
#pragma unroll
  for (int e = 0; e < 4; ++e) {
    const int rr = quad * 4 + e;
    const int rloc = mt * 16 + rr;
    const int du = 63 + lc - rr;         // [48,78]
    const int us0 = du & 15;
    const int A = (du >> 4) - mt;        // valid kk = nt + A, nt=0..3
#pragma unroll
    for (int kk = 0; kk < 8; ++kk) {
      if (kk < A || kk > A + 3) wSk[rloc * 136 + us0 + 16 * kk] = 0;
    }
  }

  // Q fragments (hi/lo split) held in registers for the whole kernel
  sx8 aQh[2], aQl[2];
  {
    const float* qrow = q + ((size_t)(bh * SS + i0 + mt * 16 + lc)) * DD;
#pragma unroll
    for (int ks = 0; ks < 2; ++ks) {
      const int koff = ks * 32 + quad * 8;
      const float4 x0 = *(const float4*)(qrow + koff);
      const float4 x1 = *(const float4*)(qrow + koff + 4);
      const float xs[8] = {x0.x, x0.y, x0.z, x0.w, x1.x, x1.y, x1.z, x1.w};
#pragma unroll
      for (int e = 0; e < 8; ++e) {
        const unsigned short hb = f2bf(xs[e]);
        aQh[ks][e] = (short)hb;
        aQl[ks][e] = (short)f2bf(xs[e] - bf2f(hb));
      }
    }
  }

  auto stageKRK = [&](const int j0) {
    for (int idx = t; idx < 1024; idx += 256) {
      const int row = idx >> 4, c4 = (idx & 15) * 4;
      const float4 x = *(const float4*)(k + ((size_t)(bh * SS + j0 + row)) * DD + c4);
      const float xs[4] = {x.x, x.y, x.z, x.w};
      sx4 h, l;
#pragma unroll
      for (int e = 0; e < 4; ++e) {
        const unsigned short hb = f2bf(xs[e]);
        h[e] = (short)hb;
        l[e] = (short)f2bf(xs[e] - bf2f(hb));
      }
      *(sx4*)&sKh[row * 72 + c4] = h;
      *(sx4*)&sKl[row * 72 + c4] = l;
    }
    const int pLo = j0 - i0 - 63 + 512;
    for (int idx = t; idx < 2048; idx += 256) {
      const int u = idx >> 4, c4 = (idx & 15) * 4;
      int p = pLo + u;
      p = p < 0 ? 0 : (p > 512 ? 512 : p);
      const float4 x = *(const float4*)(RK + (size_t)p * DD + c4);
      sx4 h;
      h[0] = (short)f2bf(x.x); h[1] = (short)f2bf(x.y);
      h[2] = (short)f2bf(x.z); h[3] = (short)f2bf(x.w);
      *(sx4*)&sRh[u * 72 + c4] = h;
    }
  };

  auto logitsTile = [&](fx4* accS1, fx4* accS2) {
#pragma unroll
    for (int ks = 0; ks < 2; ++ks) {
      const int koff = ks * 32 + quad * 8;
#pragma unroll
      for (int nt = 0; nt < 4; ++nt) {
        const sx8 bKh = *(const sx8*)&sKh[(nt * 16 + lc) * 72 + koff];
        const sx8 bKl = *(const sx8*)&sKl[(nt * 16 + lc) * 72 + koff];
        accS1[nt] = __builtin_amdgcn_mfma_f32_16x16x32_bf16(aQh[ks], bKh, accS1[nt], 0, 0, 0);
        accS1[nt] = __builtin_amdgcn_mfma_f32_16x16x32_bf16(aQl[ks], bKh, accS1[nt], 0, 0, 0);
        accS1[nt] = __builtin_amdgcn_mfma_f32_16x16x32_bf16(aQh[ks], bKl, accS1[nt], 0, 0, 0);
      }
#pragma unroll
      for (int s = 0; s < 5; ++s) {
        const sx8 bR = *(const sx8*)&sRh[((3 - mt + s) * 16 + lc) * 72 + koff];
        accS2[s] = __builtin_amdgcn_mfma_f32_16x16x32_bf16(aQh[ks], bR, accS2[s], 0, 0, 0);
      }
    }
  };

  const fx4 zz = {0.f, 0.f, 0.f, 0.f};

  // ------------------------------ pass 1: row sums -------------------------
  float sAcc[4] = {0.f, 0.f, 0.f, 0.f};
  for (int jt = 0; jt <= it; ++jt) {
    const int j0 = jt * 64;
    if (jt) __syncthreads();  // prev tile's LDS reads done
    stageKRK(j0);
    __syncthreads();
    fx4 accS1[4] = {zz, zz, zz, zz};
    fx4 accS2[5] = {zz, zz, zz, zz, zz};
    logitsTile(accS1, accS2);
#pragma unroll
    for (int nt = 0; nt < 4; ++nt) {
#pragma unroll
      for (int e = 0; e < 4; ++e) {
        const int rr = quad * 4 + e;
        const int du = 63 + lc - rr;
        const int srcLane = (lane & 48) | (du & 15);
        const float g0 = __shfl(accS2[nt][e], srcLane, 64);
        const float g1 = __shfl(accS2[nt + 1][e], srcLane, 64);
        const float val = accS1[nt][e] + (du < 64 ? g0 : g1);
        const int col = j0 + nt * 16 + lc;
        if (col <= i0 + mt * 16 + rr) sAcc[e] += __expf(val);
      }
    }
  }
  // reduce partial sums across the 16 lanes of each quad
#pragma unroll
  for (int off = 1; off <= 8; off <<= 1) {
#pragma unroll
    for (int e = 0; e < 4; ++e) sAcc[e] += __shfl_xor(sAcc[e], off, 64);
  }
  if (lc == 0) {
#pragma unroll
    for (int e = 0; e < 4; ++e) rowInv[mt * 16 + quad * 4 + e] = 1.f / sAcc[e];
  }
  __syncthreads();  // rowInv visible; pass-1 LDS reads done

  // ------------------------------ pass 2: W + O ----------------------------
  float rI[4];
#pragma unroll
  for (int e = 0; e < 4; ++e) rI[e] = rowInv[mt * 16 + quad * 4 + e];
  fx4 accO[4] = {zz, zz, zz, zz};

  for (int jt = 0; jt <= it; ++jt) {
    const int j0 = jt * 64;
    const int pLo = j0 - i0 - 63 + 512;
    if (jt) __syncthreads();  // prev tile's PV LDS reads done
    stageKRK(j0);
    __syncthreads();
    fx4 accS1[4] = {zz, zz, zz, zz};
    fx4 accS2[5] = {zz, zz, zz, zz, zz};
    logitsTile(accS1, accS2);
    __syncthreads();  // region0 reads done before overwriting with vT/rvT/wA

    // stage v^T (issue global loads early; latency hides under epilogue)
    for (int idx = t; idx < 1024; idx += 256) {
      const int jj = idx >> 4, d4 = (idx & 15) * 4;
      const float4 x4 = *(const float4*)(v + ((size_t)(bh * SS + j0 + jj)) * DD + d4);
      vT[(d4 + 0) * 72 + jj] = (short)f2bf(x4.x);
      vT[(d4 + 1) * 72 + jj] = (short)f2bf(x4.y);
      vT[(d4 + 2) * 72 + jj] = (short)f2bf(x4.z);
      vT[(d4 + 3) * 72 + jj] = (short)f2bf(x4.w);
    }
    // stage RVstaged^T
    for (int idx = t; idx < 2048; idx += 256) {
      const int u = idx >> 4, d4 = (idx & 15) * 4;
      int p = pLo + u;
      p = p < 0 ? 0 : (p > 512 ? 512 : p);
      const float4 x4 = *(const float4*)(RV + (size_t)p * DD + d4);
      rvT[(d4 + 0) * 136 + u] = (short)f2bf(x4.x);
      rvT[(d4 + 1) * 136 + u] = (short)f2bf(x4.y);
      rvT[(d4 + 2) * 136 + u] = (short)f2bf(x4.z);
      rvT[(d4 + 3) * 136 + u] = (short)f2bf(x4.w);
    }

    // epilogue: normalize, write W, stage wA + wSk (valid slots only)
#pragma unroll
    for (int nt = 0; nt < 4; ++nt) {
#pragma unroll
      for (int e = 0; e < 4; ++e) {
        const int rr = quad * 4 + e;
        const int du = 63 + lc - rr;
        const int srcLane = (lane & 48) | (du & 15);
        const float g0 = __shfl(accS2[nt][e], srcLane, 64);
        const float g1 = __shfl(accS2[nt + 1][e], srcLane, 64);
        const float val = accS1[nt][e] + (du < 64 ? g0 : g1);
        const int col = j0 + nt * 16 + lc;
        const int rowg = i0 + mt * 16 + rr;
        const float w = (col <= rowg) ? __expf(val) * rI[e] : 0.f;
        W[((size_t)(bh * SS + rowg)) * SS + col] = w;
        const unsigned short h = f2bf(w);
        wA[(mt * 16 + rr) * 72 + nt * 16 + lc] = (short)h;
        wSk[(mt * 16 + rr) * 136 + du + 16 * (nt - mt)] = (short)h;
      }
    }
    __syncthreads();  // staging complete before PV MFMAs

    // O += w @ v   (K = 64 over j)
#pragma unroll
    for (int ks = 0; ks < 2; ++ks) {
      const int koff = ks * 32 + quad * 8;
      const sx8 aW = *(const sx8*)&wA[(mt * 16 + lc) * 72 + koff];
#pragma unroll
      for (int nt = 0; nt < 4; ++nt) {
        const sx8 bV = *(const sx8*)&vT[(nt * 16 + lc) * 72 + koff];
        accO[nt] = __builtin_amdgcn_mfma_f32_16x16x32_bf16(aW, bV, accO[nt], 0, 0, 0);
      }
    }
    // O += wskew @ RVstaged   (K = 128 over u)
#pragma unroll
    for (int ks = 0; ks < 4; ++ks) {
      const int koff = ks * 32 + quad * 8;
      const sx8 aS = *(const sx8*)&wSk[(mt * 16 + lc) * 136 + koff];
#pragma unroll
      for (int nt = 0; nt < 4; ++nt) {
        const sx8 bR = *(const sx8*)&rvT[(nt * 16 + lc) * 136 + koff];
        accO[nt] = __builtin_amdgcn_mfma_f32_16x16x32_bf16(aS, bR, accO[nt], 0, 0, 0);
      }
    }
  }

  // write O (C-layout: row = quad*4+e, col = lc, per n-tile)
#pragma unroll
  for (int nt = 0; nt < 4; ++nt) {
#pragma unroll
    for (int e = 0; e < 4; ++e) {
      O[((size_t)(bh * SS + i0 + mt * 16 + quad * 4 + e)) * DD + nt * 16 + lc] = accO[nt][e];
    }
  }
}

extern "C" void kernel_launch(void* const* d_in, const int* in_sizes, int n_in,
                              void* d_out, int out_size, void* d_ws, size_t ws_size,
                              hipStream_t stream) {
  const float* q = (const float*)d_in[0];
  const float* k = (const float*)d_in[1];
  const float* v = (const float*)d_in[2];
  const float* RK = (const float*)d_in[3];  // (1025,64); causal => rows 0..512
  const float* RV = (const float*)d_in[4];

  float* O = (float*)d_out;                         // (B,H,S,D)
  float* W = (float*)d_out + (size_t)BH * SS * DD;  // (B,H,S,S)

  k_fused<<<dim3(16, BH), 256, 0, stream>>>(q, k, v, RK, RV, W, O);
}